// Round 7
// baseline (105.229 us; speedup 1.0000x reference)
//
#include <hip/hip_runtime.h>
#include <stdint.h>

// GPTQ 4-bit fused dequant-GEMM, MI355X gfx950.  Round 7.
// M=128, K=4096, N=11008, group=128, g_idx[k]=k>>7 (affine).
//
// R6 post-mortem: retile (VALU cut) moved k_gemm only ~41->37us; issue floor
// is ~4us -> latency-period-bound.  Cause: compiler emits s_waitcnt vmcnt(0)
// before EVERY s_barrier, and qweight (HBM ~900cyc) loads were issued between
// every barrier pair -> each of the 8 group-iterations pays ~an HBM latency.
// R7: hoist ALL of the block's qweight (8 groups x 4 dwords/lane = 32 VGPRs)
// and dequant constants to the prologue; the K-loop's barriers then drain only
// the L2-latency A-tile loads.  One HBM drain per block instead of eight.
//  * k_prep packs zsc[g][n] = {f16 s, f16 -(z+1)s} (half2, 1 dword) so all
//    dequant constants for 8 groups fit in 16 VGPRs; S2/Z2 derived in-loop
//    with 3 packed ops.
//  * g-loop fully unrolled so qwA[8][4]/zs2[8][2] promote to registers.
// Unchanged: split-K x4 grid (172,4), 512thr, 64mx32n wave tiles with kk-split
// + LDS pair-reduction, async dbuf A staging, exact-cancellation f16 dequant,
// f32 partials + k_reduce(bias).

#define M_DIM 128
#define K_DIM 4096
#define N_DIM 11008
#define GS    128
#define NG    32
#define SPLIT 4
#define GPB   (NG / SPLIT)   // 8 groups per block
#define PART_STRIDE ((size_t)M_DIM * N_DIM)

typedef _Float16 half8  __attribute__((ext_vector_type(8)));
typedef _Float16 half2t __attribute__((ext_vector_type(2)));
typedef _Float16 half4t __attribute__((ext_vector_type(4)));
typedef float    f32x4  __attribute__((ext_vector_type(4)));

// ---------------- prep: blocks 0..511 cvt x->f16; 512..1887 zsc ----------
__global__ void k_prep(const float* __restrict__ x, const int* __restrict__ qzeros,
                       const float* __restrict__ scales,
                       _Float16* __restrict__ xh, half2t* __restrict__ zsc) {
    int b = blockIdx.x, tid = threadIdx.x;
    if (b < 512) {                                   // 512*256*4 == 524288 exact
        int i = (b * 256 + tid) * 4;
        float4 v = *(const float4*)(x + i);
        half4t o;
        o[0] = (_Float16)v.x; o[1] = (_Float16)v.y;
        o[2] = (_Float16)v.z; o[3] = (_Float16)v.w;
        *(half4t*)(xh + i) = o;
    } else {                                         // 1376 blocks: 32 g x 43 nb
        b -= 512;
        int g = b / 43;
        int n = (b - g * 43) * 256 + tid;            // 43*256 == 11008 exact
        unsigned qz = (unsigned)qzeros[g * (N_DIM / 8) + (n >> 3)];
        float z1 = (float)((qz >> ((n & 7) * 4)) & 15u) + 1.0f;
        float s  = scales[g * N_DIM + n];
        half2t o;
        o[0] = (_Float16)s;           // f16 s: rel err 5e-4 -> ~7e-5 abs on w
        o[1] = (_Float16)(-z1 * s);   // |z1*s| <= 0.16, abs err ~6e-5
        zsc[g * N_DIM + n] = o;
    }
}

// async 16B/lane global->LDS; lds base wave-uniform, lane i -> base + i*16.
__device__ __forceinline__ void load_lds16(const void* g, void* l) {
    __builtin_amdgcn_global_load_lds(
        (const __attribute__((address_space(1))) unsigned int*)g,
        (__attribute__((address_space(3))) unsigned int*)l, 16, 0, 0);
}

// nibble pair p (nibbles 2p, 2p+1) of q -> two f16 weights:
//  t  = {0x6400|nib_lo, 0x6400|nib_hi<<4} = {1024+q_lo, 1024+16*q_hi}
//  qf = t - 1024                  (EXACT in f16: integers <= 2048)
//  w  = fma(qf, {s, s/16}, {-z1}) where z1 = (z+1)*s
// No pointer casts: pure vector ops, SROA-safe (scratch regression guard).
__device__ __forceinline__ half8 dequant8(unsigned q, half2t S2, half2t Z2) {
    const half2t BIAS = __builtin_bit_cast(half2t, 0x64006400u);
    half2t w[4];
#pragma unroll
    for (int p = 0; p < 4; ++p) {
        unsigned r = __builtin_amdgcn_perm(q, q, 0x00010001u * (unsigned)p); // byte p -> bytes 0,2
        unsigned t = (r & 0x00F0000Fu) | 0x64006400u;                        // v_and_or_b32
        w[p] = __builtin_elementwise_fma(__builtin_bit_cast(half2t, t) - BIAS, S2, Z2);
    }
    half4t lo = __builtin_shufflevector(w[0], w[1], 0, 1, 2, 3);
    half4t hi = __builtin_shufflevector(w[2], w[3], 0, 1, 2, 3);
    return __builtin_shufflevector(lo, hi, 0, 1, 2, 3, 4, 5, 6, 7);
}

// ---------------- main fused kernel ----------------
__global__ __launch_bounds__(512, 4)
void k_gemm(const _Float16* __restrict__ xh,     // [128][4096] f16
            const int*      __restrict__ qweight,// [512][11008] int32
            const half2t*   __restrict__ zsc,    // [32][11008] {s, -(z+1)s}
            float*          __restrict__ part)   // [SPLIT][128][11008] partials
{
    // Double-buffered A tile: logical (m,kb) of buffer b at
    //   As[b][m*128 + (kb ^ (m&15))*8]   (halfs)
    // Staged so chunk c = it*512+tid lands at byte offset c*16.
    __shared__ _Float16 As[2][128 * 128];   // 2 x 32 KB

    const int tid  = threadIdx.x;
    const int lane = tid & 63;
    const int w    = tid >> 6;     // 0..7
    const int wx   = w & 1;        // n offset 32*wx
    const int wy   = (w >> 1) & 1; // m offset 64*wy
    const int kh   = w >> 2;       // kk-half: kh=0 -> kk{0,1}, kh=1 -> kk{2,3}
    const int q    = lane >> 4;    // quad
    const int lr   = lane & 15;

    const int n0 = blockIdx.x * 64;
    const int g0 = blockIdx.y * GPB;
    int ncol[2] = { n0 + wx * 32 + lr, n0 + wx * 32 + lr + 16 };

    f32x4 acc[4][2];
#pragma unroll
    for (int f = 0; f < 4; ++f)
#pragma unroll
        for (int h = 0; h < 2; ++h)
            acc[f][h] = (f32x4){0.f, 0.f, 0.f, 0.f};

    // per-lane staging geometry: c = it*512 + tid; m=c>>4; kb=(c&15)^(m&15)
    int cm[4], ckb[4];
#pragma unroll
    for (int it = 0; it < 4; ++it) {
        int c = it * 512 + tid;
        cm[it]  = c >> 4;
        ckb[it] = (c & 15) ^ (cm[it] & 15);
    }
    const int wave_lds = w * 64 * 8;   // halfs

    // ---- prologue: A(0) async + FULL qweight/const hoist (one HBM drain) ----
#pragma unroll
    for (int it = 0; it < 4; ++it)
        load_lds16(xh + (size_t)cm[it] * K_DIM + g0 * GS + ckb[it] * 8,
                   &As[0][it * 512 * 8 + wave_lds]);

    unsigned qwA[GPB][4];   // 32 VGPRs: all 8 groups' B data for this wave
    half2t   zs2[GPB][2];   // 16 VGPRs: {s, -z1} per (group, h)
#pragma unroll
    for (int gg = 0; gg < GPB; ++gg) {
        int ga = g0 + gg;
#pragma unroll
        for (int t = 0; t < 2; ++t)
#pragma unroll
            for (int h = 0; h < 2; ++h)
                qwA[gg][t * 2 + h] =
                    (unsigned)qweight[(size_t)(ga * 16 + (kh * 2 + t) * 4 + q) * N_DIM + ncol[h]];
#pragma unroll
        for (int h = 0; h < 2; ++h)
            zs2[gg][h] = zsc[(size_t)ga * N_DIM + ncol[h]];
    }

#pragma unroll
    for (int g = 0; g < GPB; ++g) {
        __syncthreads();   // drains: g==0 -> everything (once); else A(g) only (L2)

        if (g + 1 < GPB) { // next A tile async, only vmem between later barriers
            int gn = g0 + g + 1;
#pragma unroll
            for (int it = 0; it < 4; ++it)
                load_lds16(xh + (size_t)cm[it] * K_DIM + gn * GS + ckb[it] * 8,
                           &As[(g + 1) & 1][it * 512 * 8 + wave_lds]);
        }

        // S2={s, s/16}, Z2={-z1,-z1} from packed zs2 (3 pk-ops per h)
        const half2t SC = { (_Float16)1.0f, (_Float16)0.0625f };
        half2t S2[2], Z2[2];
#pragma unroll
        for (int h = 0; h < 2; ++h) {
            half2t ss = __builtin_shufflevector(zs2[g][h], zs2[g][h], 0, 0);
            S2[h] = ss * SC;
            Z2[h] = __builtin_shufflevector(zs2[g][h], zs2[g][h], 1, 1);
        }

#pragma unroll
        for (int t = 0; t < 2; ++t) {
            const int kk = kh * 2 + t;
            half8 bf[2];
#pragma unroll
            for (int h = 0; h < 2; ++h)
                bf[h] = dequant8(qwA[g][t * 2 + h], S2[h], Z2[h]);
#pragma unroll
            for (int f = 0; f < 4; ++f) {
                int m   = wy * 64 + f * 16 + lr;
                int kb2 = (kk * 4 + q) ^ lr;     // m&15 == lr
                half8 af = *(const half8*)(&As[g & 1][m * 128 + kb2 * 8]);
#pragma unroll
                for (int h = 0; h < 2; ++h)
                    acc[f][h] = __builtin_amdgcn_mfma_f32_16x16x32_f16(af, bf[h], acc[f][h], 0, 0, 0);
            }
        }
    }

    // ---- pair reduction (w, w^4) through LDS, then store partials ----
    __syncthreads();                       // all A reads done; LDS reusable
    float* red = (float*)&As[0][0];        // 32 KB: 4 pairs x 8 KB
    const int pid = w & 3;
    if (w >= 4) {
#pragma unroll
        for (int f = 0; f < 4; ++f)
#pragma unroll
            for (int h = 0; h < 2; ++h)
                *(f32x4*)(red + pid * 2048 + (f * 2 + h) * 256 + lane * 4) = acc[f][h];
    }
    __syncthreads();
    if (w < 4) {
        float* po = part + (size_t)blockIdx.y * PART_STRIDE;
#pragma unroll
        for (int f = 0; f < 4; ++f) {
            int mrow = wy * 64 + f * 16 + q * 4;
#pragma unroll
            for (int h = 0; h < 2; ++h) {
                f32x4 o = acc[f][h] + *(const f32x4*)(red + pid * 2048 + (f * 2 + h) * 256 + lane * 4);
#pragma unroll
                for (int r = 0; r < 4; ++r)
                    po[(size_t)(mrow + r) * N_DIM + ncol[h]] = o[r];
            }
        }
    }
}

// ---------------- reduce: out = bias + sum_s part[s] ----------------
__global__ void k_reduce(const float* __restrict__ part, const float* __restrict__ bias,
                         float* __restrict__ out) {
    int i = (blockIdx.x * 256 + threadIdx.x) * 4;   // 1376 blocks: 128*11008 exact
    int m = i / N_DIM;
    int n = i - m * N_DIM;                           // N_DIM%4==0 -> n%4==0
    f32x4 s = *(const f32x4*)(bias + n);
#pragma unroll
    for (int sp = 0; sp < SPLIT; ++sp)
        s += *(const f32x4*)(part + sp * PART_STRIDE + i);
    *(f32x4*)(out + i) = s;
}

extern "C" void kernel_launch(void* const* d_in, const int* in_sizes, int n_in,
                              void* d_out, int out_size, void* d_ws, size_t ws_size,
                              hipStream_t stream) {
    const float* x       = (const float*)d_in[0];
    const int*   qweight = (const int*)d_in[1];
    const int*   qzeros  = (const int*)d_in[2];
    const float* scales  = (const float*)d_in[3];
    const float* bias    = (const float*)d_in[4];
    // d_in[5] = g_idx, affine by construction -> unused

    char* ws = (char*)d_ws;
    _Float16* xh   = (_Float16*)ws;                              // 1,048,576 B
    half2t*   zsc  = (half2t*)(ws + 1048576);                    // 1,409,024 B
    float*    part = (float*)(ws + 1048576 + 1409024);           // 4 x 5,636,096 B

    k_prep  <<<dim3(1888),            dim3(256), 0, stream>>>(x, qzeros, scales, xh, zsc);
    k_gemm  <<<dim3(N_DIM/64, SPLIT), dim3(512), 0, stream>>>(xh, qweight, zsc, part);
    k_reduce<<<dim3(1376),            dim3(256), 0, stream>>>(part, bias, (float*)d_out);
}